// Round 1
// baseline (1412.780 us; speedup 1.0000x reference)
//
#include <hip/hip_runtime.h>
#include <math.h>

// ---------------------------------------------------------------- CSR build
__global__ void fill_ones_k(int* __restrict__ p, int n) {
  int i = blockIdx.x * blockDim.x + threadIdx.x;
  if (i < n) p[i] = 1;  // self-loop contributes 1 to every node's in-degree
}

__global__ void count_edges_k(const int* __restrict__ dst, int E, int* __restrict__ cnt) {
  int i = blockIdx.x * blockDim.x + threadIdx.x;
  if (i < E) atomicAdd(&cnt[dst[i]], 1);
}

// exclusive scan over n (<= ~20k) entries, single block of 1024 threads
__global__ void scan_k(const int* __restrict__ cnt, int* __restrict__ indptr, int n) {
  __shared__ int lds[1024];
  __shared__ int carry_s;
  int t = threadIdx.x;
  if (t == 0) carry_s = 0;
  __syncthreads();
  for (int base = 0; base < n; base += 1024) {
    int i = base + t;
    int v = (i < n) ? cnt[i] : 0;
    lds[t] = v;
    __syncthreads();
    for (int off = 1; off < 1024; off <<= 1) {
      int add = (t >= off) ? lds[t - off] : 0;
      __syncthreads();
      lds[t] += add;
      __syncthreads();
    }
    int carry = carry_s;
    if (i < n) indptr[i] = carry + lds[t] - v;
    __syncthreads();
    if (t == 1023) carry_s = carry + lds[1023];
    __syncthreads();
  }
  if (t == 0) indptr[n] = carry_s;
}

__global__ void copy_k(const int* __restrict__ a, int* __restrict__ b, int n) {
  int i = blockIdx.x * blockDim.x + threadIdx.x;
  if (i < n) b[i] = a[i];
}

__global__ void scatter_k(const int* __restrict__ src, const int* __restrict__ dst, int E, int n,
                          int* __restrict__ cursor, int* __restrict__ esrc) {
  int i = blockIdx.x * blockDim.x + threadIdx.x;
  if (i < E) {
    int p = atomicAdd(&cursor[dst[i]], 1);
    esrc[p] = src[i];
  } else if (i < E + n) {
    int node = i - E;
    int p = atomicAdd(&cursor[node], 1);
    esrc[p] = node;  // self loop
  }
}

// ---------------------------------------------------------------- fp32 GEMM
// C[M,Nc] = A[M,K] @ B[K,Nc] (+bias). 128x128 tile, BK=8, 256 thr, 8x8/thread.
template<bool ADD_BIAS>
__global__ __launch_bounds__(256) void gemm_f32(const float* __restrict__ A,
                                                const float* __restrict__ B,
                                                const float* __restrict__ bias,
                                                float* __restrict__ C,
                                                int M, int K, int Nc) {
  __shared__ float As[8][128];
  __shared__ float Bs[8][128];
  const int bm = blockIdx.y * 128, bn = blockIdx.x * 128;
  const int t = threadIdx.x;
  const int arow = t >> 1, ak = (t & 1) * 4;      // A: 128 rows x 8 k, float4
  const int brow = t >> 5, bcol = (t & 31) * 4;   // B: 8 rows x 128 cols, float4
  const int ty = t >> 4, tx = t & 15;
  float acc[8][8] = {};
  for (int k0 = 0; k0 < K; k0 += 8) {
    float4 av = make_float4(0.f, 0.f, 0.f, 0.f);
    if (bm + arow < M) av = *(const float4*)&A[(size_t)(bm + arow) * K + k0 + ak];
    As[ak + 0][arow] = av.x; As[ak + 1][arow] = av.y;
    As[ak + 2][arow] = av.z; As[ak + 3][arow] = av.w;
    float4 bv = make_float4(0.f, 0.f, 0.f, 0.f);
    if (bn + bcol < Nc) bv = *(const float4*)&B[(size_t)(k0 + brow) * Nc + bn + bcol];
    *(float4*)&Bs[brow][bcol] = bv;
    __syncthreads();
#pragma unroll
    for (int k = 0; k < 8; ++k) {
      float a[8], b[8];
#pragma unroll
      for (int j = 0; j < 8; ++j) a[j] = As[k][ty * 8 + j];
#pragma unroll
      for (int j = 0; j < 8; ++j) b[j] = Bs[k][tx * 8 + j];
#pragma unroll
      for (int i = 0; i < 8; ++i)
#pragma unroll
        for (int j = 0; j < 8; ++j) acc[i][j] += a[i] * b[j];
    }
    __syncthreads();
  }
  for (int i = 0; i < 8; ++i) {
    int r = bm + ty * 8 + i;
    if (r >= M) break;
    for (int j = 0; j < 8; j += 4) {
      int c = bn + tx * 8 + j;
      if (c < Nc) {
        float4 v = make_float4(acc[i][j], acc[i][j + 1], acc[i][j + 2], acc[i][j + 3]);
        if (ADD_BIAS) { v.x += bias[c]; v.y += bias[c + 1]; v.z += bias[c + 2]; v.w += bias[c + 3]; }
        *(float4*)&C[(size_t)r * Nc + c] = v;
      }
    }
  }
}

// ---------------------------------------------------------------- logits s,d
template<int H, int C>
__global__ __launch_bounds__(256) void logits_k(const float* __restrict__ h,
                                                const float* __restrict__ a_src,
                                                const float* __restrict__ a_dst,
                                                float* __restrict__ s, float* __restrict__ d) {
  const int node = blockIdx.x;
  const int wave = threadIdx.x >> 6, lane = threadIdx.x & 63;
  for (int hd = wave; hd < H; hd += 4) {
    float ss = 0.f, dd = 0.f;
    const float* hp = h + (size_t)node * H * C + hd * C;
    for (int c = lane; c < C; c += 64) {
      float v = hp[c];
      ss += v * a_src[hd * C + c];
      dd += v * a_dst[hd * C + c];
    }
    for (int off = 32; off; off >>= 1) {
      ss += __shfl_xor(ss, off);
      dd += __shfl_xor(dd, off);
    }
    if (lane == 0) { s[node * H + hd] = ss; d[node * H + hd] = dd; }
  }
}

// ---------------------------------------------------------------- attention + aggregate (+bias+skip+act)
template<int H, int C, bool ELU_OUT, bool MEAN_HEADS>
__global__ __launch_bounds__(256) void attn_k(const float* __restrict__ hfeat,
                                              const float* __restrict__ sbuf,
                                              const float* __restrict__ dbuf,
                                              const int* __restrict__ indptr,
                                              const int* __restrict__ esrc,
                                              const float* __restrict__ bias,
                                              const float* __restrict__ skip,
                                              float* __restrict__ out) {
  constexpr int F = H * C;
  constexpr int CPT = (F + 255) / 256;   // 4 (F=1024) or 2 (F=384)
  constexpr int CH = 256 / H;            // edge chunk: 64 (H=4), 42 (H=6)
  __shared__ float m_l[H], invden_l[H], d_l[H];
  __shared__ float alpha_l[CH * H];
  __shared__ int src_l[CH];
  __shared__ float accs[MEAN_HEADS ? F : 4];

  const int node = blockIdx.x;
  const int t = threadIdx.x;
  const int beg = indptr[node];
  const int deg = indptr[node + 1] - beg;
  if (t < H) d_l[t] = dbuf[node * H + t];
  __syncthreads();

  // phase 1: per-head max and denom over incoming edges (wave per head)
  const int wave = t >> 6, lane = t & 63;
  for (int hd = wave; hd < H; hd += 4) {
    const float dn = d_l[hd];
    float mx = -1e30f;
    for (int i = lane; i < deg; i += 64) {
      int se = esrc[beg + i];
      float e = sbuf[se * H + hd] + dn;
      e = fmaxf(e, 0.2f * e);  // leaky relu
      mx = fmaxf(mx, e);
    }
    for (int off = 32; off; off >>= 1) mx = fmaxf(mx, __shfl_xor(mx, off));
    float den = 0.f;
    for (int i = lane; i < deg; i += 64) {
      int se = esrc[beg + i];
      float e = sbuf[se * H + hd] + dn;
      e = fmaxf(e, 0.2f * e);
      den += __expf(e - mx);
    }
    for (int off = 32; off; off >>= 1) den += __shfl_xor(den, off);
    if (lane == 0) { m_l[hd] = mx; invden_l[hd] = 1.f / den; }
  }
  __syncthreads();

  // phase 2: chunked alpha + feature accumulation
  float acc[CPT] = {};
  const int c0 = t * CPT;
  const int myhead = c0 / C;
  for (int cb = 0; cb < deg; cb += CH) {
    const int ce = min(CH, deg - cb);
    if (t < ce * H) {
      int e_i = t / H, hd = t % H;
      int se = esrc[beg + cb + e_i];
      if (hd == 0) src_l[e_i] = se;
      float e = sbuf[se * H + hd] + d_l[hd];
      e = fmaxf(e, 0.2f * e);
      alpha_l[e_i * H + hd] = __expf(e - m_l[hd]) * invden_l[hd];
    }
    __syncthreads();
    if (c0 < F) {
      for (int e_i = 0; e_i < ce; ++e_i) {
        int se = src_l[e_i];
        float al = alpha_l[e_i * H + myhead];
        const float* hp = hfeat + (size_t)se * F + c0;
        if (CPT == 4) {
          float4 v = *(const float4*)hp;
          acc[0] += al * v.x; acc[1] += al * v.y; acc[2] += al * v.z; acc[3] += al * v.w;
        } else {
          float2 v = *(const float2*)hp;
          acc[0] += al * v.x; acc[1] += al * v.y;
        }
      }
    }
    __syncthreads();
  }

  // epilogue
  if (!MEAN_HEADS) {
    if (c0 < F) {
      float r[4];
#pragma unroll
      for (int j = 0; j < CPT; ++j) {
        float x = acc[j] + bias[c0 + j] + skip[(size_t)node * F + c0 + j];
        if (ELU_OUT) x = x > 0.f ? x : __expf(x) - 1.f;
        r[j] = x;
      }
      *(float4*)&out[(size_t)node * F + c0] = make_float4(r[0], r[1], r[2], r[3]);
    }
  } else {
    if (c0 < F) { accs[c0] = acc[0]; accs[c0 + 1] = acc[1]; }
    __syncthreads();
    if (t < C) {
      float sum = 0.f;
#pragma unroll
      for (int hd = 0; hd < H; ++hd) sum += accs[hd * C + t];
      out[(size_t)node * C + t] = sum * (1.f / (float)H) + bias[t] + skip[(size_t)node * C + t];
    }
  }
}

// ---------------------------------------------------------------- launch
extern "C" void kernel_launch(void* const* d_in, const int* in_sizes, int n_in,
                              void* d_out, int out_size, void* d_ws, size_t ws_size,
                              hipStream_t stream) {
  const float* x      = (const float*)d_in[0];
  const int*   ei     = (const int*)d_in[1];
  const float* W1     = (const float*)d_in[2];
  const float* a1s    = (const float*)d_in[3];
  const float* a1d    = (const float*)d_in[4];
  const float* b1     = (const float*)d_in[5];
  const float* lin1W  = (const float*)d_in[6];
  const float* lin1b  = (const float*)d_in[7];
  const float* W2     = (const float*)d_in[8];
  const float* a2s    = (const float*)d_in[9];
  const float* a2d    = (const float*)d_in[10];
  const float* b2     = (const float*)d_in[11];
  const float* lin2W  = (const float*)d_in[12];
  const float* lin2b  = (const float*)d_in[13];
  const float* W3     = (const float*)d_in[14];
  const float* a3s    = (const float*)d_in[15];
  const float* a3d    = (const float*)d_in[16];
  const float* b3     = (const float*)d_in[17];
  const float* lin3W  = (const float*)d_in[18];
  const float* lin3b  = (const float*)d_in[19];

  const int N = in_sizes[0] / 128;
  const int E = in_sizes[1] / 2;
  const int* src = ei;
  const int* dst = ei + E;

  char* ws = (char*)d_ws;
  size_t off = 0;
  auto alloc = [&](size_t bytes) -> void* {
    void* p = ws + off;
    off += (bytes + 255) & ~(size_t)255;
    return p;
  };
  float* h    = (float*)alloc((size_t)N * 1024 * 4);
  float* act  = (float*)alloc((size_t)N * 1024 * 4);
  float* skip = (float*)alloc((size_t)N * 1024 * 4);
  float* sb   = (float*)alloc((size_t)N * 6 * 4);
  float* db   = (float*)alloc((size_t)N * 6 * 4);
  int* indptr = (int*)alloc((size_t)(N + 1) * 4);
  int* cursor = (int*)alloc((size_t)N * 4);
  int* esrc   = (int*)alloc((size_t)(E + N) * 4);

  // ---- CSR over dst (self loops appended)
  fill_ones_k<<<(N + 255) / 256, 256, 0, stream>>>(cursor, N);
  count_edges_k<<<(E + 255) / 256, 256, 0, stream>>>(dst, E, cursor);
  scan_k<<<1, 1024, 0, stream>>>(cursor, indptr, N);
  copy_k<<<(N + 255) / 256, 256, 0, stream>>>(indptr, cursor, N);
  scatter_k<<<(E + N + 255) / 256, 256, 0, stream>>>(src, dst, E, N, cursor, esrc);

  dim3 gWide((1024 + 127) / 128, (N + 127) / 128);
  // ---- Layer 1
  gemm_f32<false><<<gWide, 256, 0, stream>>>(x, W1, nullptr, h, N, 128, 1024);
  gemm_f32<true ><<<gWide, 256, 0, stream>>>(x, lin1W, lin1b, skip, N, 128, 1024);
  logits_k<4, 256><<<N, 256, 0, stream>>>(h, a1s, a1d, sb, db);
  attn_k<4, 256, true, false><<<N, 256, 0, stream>>>(h, sb, db, indptr, esrc, b1, skip, act);
  // ---- Layer 2
  gemm_f32<false><<<gWide, 256, 0, stream>>>(act, W2, nullptr, h, N, 1024, 1024);
  gemm_f32<true ><<<gWide, 256, 0, stream>>>(act, lin2W, lin2b, skip, N, 1024, 1024);
  logits_k<4, 256><<<N, 256, 0, stream>>>(h, a2s, a2d, sb, db);
  attn_k<4, 256, true, false><<<N, 256, 0, stream>>>(h, sb, db, indptr, esrc, b2, skip, act);
  // ---- Layer 3
  dim3 g3((384 + 127) / 128, (N + 127) / 128);
  gemm_f32<false><<<g3, 256, 0, stream>>>(act, W3, nullptr, h, N, 1024, 384);
  dim3 g4(1, (N + 127) / 128);
  gemm_f32<true ><<<g4, 256, 0, stream>>>(act, lin3W, lin3b, skip, N, 1024, 64);
  logits_k<6, 64><<<N, 256, 0, stream>>>(h, a3s, a3d, sb, db);
  attn_k<6, 64, false, true><<<N, 256, 0, stream>>>(h, sb, db, indptr, esrc, b3, skip, (float*)d_out);
}

// Round 2
// 520.131 us; speedup vs baseline: 2.7162x; 2.7162x over previous
//
#include <hip/hip_runtime.h>
#include <math.h>

typedef unsigned short ushort_t;
typedef __attribute__((ext_vector_type(8))) short bf16x8;
typedef __attribute__((ext_vector_type(4))) float f32x4;

__device__ __forceinline__ ushort_t f2bf(float f) {
  unsigned u = __float_as_uint(f);
  unsigned r = (u + 0x7FFF + ((u >> 16) & 1)) >> 16;  // RNE
  return (ushort_t)r;
}

__device__ __forceinline__ void gload_lds16(const void* g, void* l) {
  __builtin_amdgcn_global_load_lds(
      (const __attribute__((address_space(1))) void*)g,
      (__attribute__((address_space(3))) void*)l, 16, 0, 0);
}

// ---------------------------------------------------------------- CSR build
__global__ void fill_ones_k(int* __restrict__ p, int n) {
  int i = blockIdx.x * blockDim.x + threadIdx.x;
  if (i < n) p[i] = 1;  // self-loop contributes 1 to every node's in-degree
}

__global__ void count_edges_k(const int* __restrict__ dst, int E, int* __restrict__ cnt) {
  int i = blockIdx.x * blockDim.x + threadIdx.x;
  if (i < E) atomicAdd(&cnt[dst[i]], 1);
}

__global__ void scan_k(const int* __restrict__ cnt, int* __restrict__ indptr, int n) {
  __shared__ int lds[1024];
  __shared__ int carry_s;
  int t = threadIdx.x;
  if (t == 0) carry_s = 0;
  __syncthreads();
  for (int base = 0; base < n; base += 1024) {
    int i = base + t;
    int v = (i < n) ? cnt[i] : 0;
    lds[t] = v;
    __syncthreads();
    for (int off = 1; off < 1024; off <<= 1) {
      int add = (t >= off) ? lds[t - off] : 0;
      __syncthreads();
      lds[t] += add;
      __syncthreads();
    }
    int carry = carry_s;
    if (i < n) indptr[i] = carry + lds[t] - v;
    __syncthreads();
    if (t == 1023) carry_s = carry + lds[1023];
    __syncthreads();
  }
  if (t == 0) indptr[n] = carry_s;
}

__global__ void copy_k(const int* __restrict__ a, int* __restrict__ b, int n) {
  int i = blockIdx.x * blockDim.x + threadIdx.x;
  if (i < n) b[i] = a[i];
}

__global__ void scatter_k(const int* __restrict__ src, const int* __restrict__ dst, int E, int n,
                          int* __restrict__ cursor, int* __restrict__ esrc) {
  int i = blockIdx.x * blockDim.x + threadIdx.x;
  if (i < E) {
    int p = atomicAdd(&cursor[dst[i]], 1);
    esrc[p] = src[i];
  } else if (i < E + n) {
    int node = i - E;
    int p = atomicAdd(&cursor[node], 1);
    esrc[p] = node;  // self loop
  }
}

// ---------------------------------------------------------------- conversions
__global__ void cast_bf16_k(const float* __restrict__ in, ushort_t* __restrict__ out, int n4) {
  int i = blockIdx.x * blockDim.x + threadIdx.x;
  if (i < n4) {
    float4 v = ((const float4*)in)[i];
    ushort_t o0 = f2bf(v.x), o1 = f2bf(v.y), o2 = f2bf(v.z), o3 = f2bf(v.w);
    ushort_t* p = out + i * 4;
    p[0] = o0; p[1] = o1; p[2] = o2; p[3] = o3;
  }
}

// W [K][N] fp32 -> WT [N][K] bf16
__global__ __launch_bounds__(256) void transpose_cast_k(const float* __restrict__ W,
                                                        ushort_t* __restrict__ WT,
                                                        int K, int N) {
  __shared__ float tile[32][33];
  const int bx = blockIdx.x * 32;  // N dim
  const int by = blockIdx.y * 32;  // K dim
  const int tx = threadIdx.x & 31, ty = threadIdx.x >> 5;  // 32x8
  for (int i = ty; i < 32; i += 8) {
    int r = by + i, c = bx + tx;
    tile[i][tx] = (r < K && c < N) ? W[(size_t)r * N + c] : 0.f;
  }
  __syncthreads();
  for (int i = ty; i < 32; i += 8) {
    int r = bx + i, c = by + tx;
    if (r < N && c < K) WT[(size_t)r * K + c] = f2bf(tile[tx][i]);
  }
}

// ---------------------------------------------------------------- bf16 MFMA GEMM
// C[M,Nc] = A[M,K](bf16) @ BT[Nc,K](bf16)^T (+bias). 128x128 tile, BK=32,
// 256 thr (4 waves, 2x2), 16x16x32 MFMA, global_load_lds staging,
// XOR slot-swizzle for conflict-free ds_read_b128.
template<bool ADD_BIAS>
__global__ __launch_bounds__(256) void gemm_bf16(const ushort_t* __restrict__ A,
                                                 const ushort_t* __restrict__ BT,
                                                 const float* __restrict__ bias,
                                                 float* __restrict__ C,
                                                 int M, int K, int Nc) {
  __shared__ ushort_t As[128 * 32];
  __shared__ ushort_t Bs[128 * 32];
  const int bm = blockIdx.y * 128, bn = blockIdx.x * 128;
  const int t = threadIdx.x;
  const int l = t & 63, wid = t >> 6;
  const int wm = wid >> 1, wn = wid & 1;

  // staging: segment seg = wid*2+i covers tile rows seg*16..seg*16+15
  size_t goffA[2], goffB[2];
  for (int i = 0; i < 2; ++i) {
    int seg = wid * 2 + i;
    int row = seg * 16 + (l >> 2);
    int p = l & 3;
    int ls = p ^ ((row >> 1) & 3);  // inverse-swizzled source slot
    int ga = min(bm + row, M - 1);
    int gb = min(bn + row, Nc - 1);
    goffA[i] = (size_t)ga * K + ls * 8;
    goffB[i] = (size_t)gb * K + ls * 8;
  }
  ushort_t* ldsA0 = &As[(wid * 2 + 0) * 512];
  ushort_t* ldsA1 = &As[(wid * 2 + 1) * 512];
  ushort_t* ldsB0 = &Bs[(wid * 2 + 0) * 512];
  ushort_t* ldsB1 = &Bs[(wid * 2 + 1) * 512];

  // fragment read addresses (swizzled)
  const int lr = l & 15, s = l >> 4;
  int raddrA[4], raddrB[4];
  for (int m = 0; m < 4; ++m) {
    int rowA = wm * 64 + m * 16 + lr;
    raddrA[m] = rowA * 32 + (s ^ ((rowA >> 1) & 3)) * 8;
    int rowB = wn * 64 + m * 16 + lr;
    raddrB[m] = rowB * 32 + (s ^ ((rowB >> 1) & 3)) * 8;
  }

  f32x4 acc[4][4] = {};
  for (int k0 = 0; k0 < K; k0 += 32) {
    gload_lds16(A + goffA[0] + k0, ldsA0);
    gload_lds16(A + goffA[1] + k0, ldsA1);
    gload_lds16(BT + goffB[0] + k0, ldsB0);
    gload_lds16(BT + goffB[1] + k0, ldsB1);
    __syncthreads();
    bf16x8 a[4], b[4];
#pragma unroll
    for (int m = 0; m < 4; ++m) a[m] = *(const bf16x8*)&As[raddrA[m]];
#pragma unroll
    for (int n = 0; n < 4; ++n) b[n] = *(const bf16x8*)&Bs[raddrB[n]];
#pragma unroll
    for (int m = 0; m < 4; ++m)
#pragma unroll
      for (int n = 0; n < 4; ++n)
        acc[m][n] = __builtin_amdgcn_mfma_f32_16x16x32_bf16(a[m], b[n], acc[m][n], 0, 0, 0);
    __syncthreads();
  }

  // epilogue: C/D layout col = lane&15, row = (lane>>4)*4 + j
#pragma unroll
  for (int n = 0; n < 4; ++n) {
    int col = bn + wn * 64 + n * 16 + (l & 15);
    if (col >= Nc) continue;
    float bv = ADD_BIAS ? bias[col] : 0.f;
#pragma unroll
    for (int m = 0; m < 4; ++m) {
#pragma unroll
      for (int j = 0; j < 4; ++j) {
        int row = bm + wm * 64 + m * 16 + (l >> 4) * 4 + j;
        if (row < M) C[(size_t)row * Nc + col] = acc[m][n][j] + bv;
      }
    }
  }
}

// ---------------------------------------------------------------- logits s,d
template<int H, int C>
__global__ __launch_bounds__(256) void logits_k(const float* __restrict__ h,
                                                const float* __restrict__ a_src,
                                                const float* __restrict__ a_dst,
                                                float* __restrict__ s, float* __restrict__ d) {
  const int node = blockIdx.x;
  const int wave = threadIdx.x >> 6, lane = threadIdx.x & 63;
  for (int hd = wave; hd < H; hd += 4) {
    float ss = 0.f, dd = 0.f;
    const float* hp = h + (size_t)node * H * C + hd * C;
    for (int c = lane; c < C; c += 64) {
      float v = hp[c];
      ss += v * a_src[hd * C + c];
      dd += v * a_dst[hd * C + c];
    }
    for (int off = 32; off; off >>= 1) {
      ss += __shfl_xor(ss, off);
      dd += __shfl_xor(dd, off);
    }
    if (lane == 0) { s[node * H + hd] = ss; d[node * H + hd] = dd; }
  }
}

// ---------------------------------------------------------------- attention + aggregate
// !MEAN_HEADS: writes bf16 [N][F] (next layer's GEMM A operand), with ELU+skip+bias.
// MEAN_HEADS: writes fp32 [N][C] final output.
template<int H, int C, bool ELU_OUT, bool MEAN_HEADS>
__global__ __launch_bounds__(256) void attn_k(const float* __restrict__ hfeat,
                                              const float* __restrict__ sbuf,
                                              const float* __restrict__ dbuf,
                                              const int* __restrict__ indptr,
                                              const int* __restrict__ esrc,
                                              const float* __restrict__ bias,
                                              const float* __restrict__ skip,
                                              void* __restrict__ out_v) {
  constexpr int F = H * C;
  constexpr int CPT = (F + 255) / 256;   // 4 (F=1024) or 2 (F=384)
  constexpr int CH = 256 / H;            // edge chunk: 64 (H=4), 42 (H=6)
  __shared__ float m_l[H], invden_l[H], d_l[H];
  __shared__ float alpha_l[CH * H];
  __shared__ int src_l[CH];
  __shared__ float accs[MEAN_HEADS ? F : 4];

  const int node = blockIdx.x;
  const int t = threadIdx.x;
  const int beg = indptr[node];
  const int deg = indptr[node + 1] - beg;
  if (t < H) d_l[t] = dbuf[node * H + t];
  __syncthreads();

  const int wave = t >> 6, lane = t & 63;
  for (int hd = wave; hd < H; hd += 4) {
    const float dn = d_l[hd];
    float mx = -1e30f;
    for (int i = lane; i < deg; i += 64) {
      int se = esrc[beg + i];
      float e = sbuf[se * H + hd] + dn;
      e = fmaxf(e, 0.2f * e);  // leaky relu
      mx = fmaxf(mx, e);
    }
    for (int off = 32; off; off >>= 1) mx = fmaxf(mx, __shfl_xor(mx, off));
    float den = 0.f;
    for (int i = lane; i < deg; i += 64) {
      int se = esrc[beg + i];
      float e = sbuf[se * H + hd] + dn;
      e = fmaxf(e, 0.2f * e);
      den += __expf(e - mx);
    }
    for (int off = 32; off; off >>= 1) den += __shfl_xor(den, off);
    if (lane == 0) { m_l[hd] = mx; invden_l[hd] = 1.f / den; }
  }
  __syncthreads();

  float acc[CPT] = {};
  const int c0 = t * CPT;
  const int myhead = c0 / C;
  for (int cb = 0; cb < deg; cb += CH) {
    const int ce = min(CH, deg - cb);
    if (t < ce * H) {
      int e_i = t / H, hd = t % H;
      int se = esrc[beg + cb + e_i];
      if (hd == 0) src_l[e_i] = se;
      float e = sbuf[se * H + hd] + d_l[hd];
      e = fmaxf(e, 0.2f * e);
      alpha_l[e_i * H + hd] = __expf(e - m_l[hd]) * invden_l[hd];
    }
    __syncthreads();
    if (c0 < F) {
      for (int e_i = 0; e_i < ce; ++e_i) {
        int se = src_l[e_i];
        float al = alpha_l[e_i * H + myhead];
        const float* hp = hfeat + (size_t)se * F + c0;
        if (CPT == 4) {
          float4 v = *(const float4*)hp;
          acc[0] += al * v.x; acc[1] += al * v.y; acc[2] += al * v.z; acc[3] += al * v.w;
        } else {
          float2 v = *(const float2*)hp;
          acc[0] += al * v.x; acc[1] += al * v.y;
        }
      }
    }
    __syncthreads();
  }

  if (!MEAN_HEADS) {
    if (c0 < F) {
      ushort_t* out = (ushort_t*)out_v;
      ushort_t r[CPT];
#pragma unroll
      for (int j = 0; j < CPT; ++j) {
        float x = acc[j] + bias[c0 + j] + skip[(size_t)node * F + c0 + j];
        if (ELU_OUT) x = x > 0.f ? x : __expf(x) - 1.f;
        r[j] = f2bf(x);
      }
      if (CPT == 4) {
        ushort4 o; o.x = r[0]; o.y = r[1]; o.z = r[2]; o.w = r[3];
        *(ushort4*)&out[(size_t)node * F + c0] = o;
      } else {
        out[(size_t)node * F + c0] = r[0];
        out[(size_t)node * F + c0 + 1] = r[1];
      }
    }
  } else {
    float* out = (float*)out_v;
    if (c0 < F) { accs[c0] = acc[0]; accs[c0 + 1] = acc[1]; }
    __syncthreads();
    if (t < C) {
      float sum = 0.f;
#pragma unroll
      for (int hd = 0; hd < H; ++hd) sum += accs[hd * C + t];
      out[(size_t)node * C + t] = sum * (1.f / (float)H) + bias[t] + skip[(size_t)node * C + t];
    }
  }
}

// ---------------------------------------------------------------- launch
extern "C" void kernel_launch(void* const* d_in, const int* in_sizes, int n_in,
                              void* d_out, int out_size, void* d_ws, size_t ws_size,
                              hipStream_t stream) {
  const float* x      = (const float*)d_in[0];
  const int*   ei     = (const int*)d_in[1];
  const float* W1     = (const float*)d_in[2];
  const float* a1s    = (const float*)d_in[3];
  const float* a1d    = (const float*)d_in[4];
  const float* b1     = (const float*)d_in[5];
  const float* lin1W  = (const float*)d_in[6];
  const float* lin1b  = (const float*)d_in[7];
  const float* W2     = (const float*)d_in[8];
  const float* a2s    = (const float*)d_in[9];
  const float* a2d    = (const float*)d_in[10];
  const float* b2     = (const float*)d_in[11];
  const float* lin2W  = (const float*)d_in[12];
  const float* lin2b  = (const float*)d_in[13];
  const float* W3     = (const float*)d_in[14];
  const float* a3s    = (const float*)d_in[15];
  const float* a3d    = (const float*)d_in[16];
  const float* b3     = (const float*)d_in[17];
  const float* lin3W  = (const float*)d_in[18];
  const float* lin3b  = (const float*)d_in[19];

  const int N = in_sizes[0] / 128;
  const int E = in_sizes[1] / 2;
  const int* src = ei;
  const int* dst = ei + E;

  char* ws = (char*)d_ws;
  size_t off = 0;
  auto alloc = [&](size_t bytes) -> void* {
    void* p = ws + off;
    off += (bytes + 255) & ~(size_t)255;
    return p;
  };
  float*    h      = (float*)alloc((size_t)N * 1024 * 4);
  float*    skip   = (float*)alloc((size_t)N * 1024 * 4);
  ushort_t* act_bf = (ushort_t*)alloc((size_t)N * 1024 * 2);
  ushort_t* x_bf   = (ushort_t*)alloc((size_t)N * 128 * 2);
  ushort_t* W1T    = (ushort_t*)alloc((size_t)1024 * 128 * 2);
  ushort_t* l1WT   = (ushort_t*)alloc((size_t)1024 * 128 * 2);
  ushort_t* W2T    = (ushort_t*)alloc((size_t)1024 * 1024 * 2);
  ushort_t* l2WT   = (ushort_t*)alloc((size_t)1024 * 1024 * 2);
  ushort_t* W3T    = (ushort_t*)alloc((size_t)384 * 1024 * 2);
  ushort_t* l3WT   = (ushort_t*)alloc((size_t)64 * 1024 * 2);
  float*    sb     = (float*)alloc((size_t)N * 6 * 4);
  float*    db     = (float*)alloc((size_t)N * 6 * 4);
  int*      indptr = (int*)alloc((size_t)(N + 1) * 4);
  int*      cursor = (int*)alloc((size_t)N * 4);
  int*      esrc   = (int*)alloc((size_t)(E + N) * 4);

  // ---- conversions (weights once; x once)
  cast_bf16_k<<<(N * 128 / 4 + 255) / 256, 256, 0, stream>>>(x, x_bf, N * 128 / 4);
  transpose_cast_k<<<dim3(32, 4), 256, 0, stream>>>(W1, W1T, 128, 1024);
  transpose_cast_k<<<dim3(32, 4), 256, 0, stream>>>(lin1W, l1WT, 128, 1024);
  transpose_cast_k<<<dim3(32, 32), 256, 0, stream>>>(W2, W2T, 1024, 1024);
  transpose_cast_k<<<dim3(32, 32), 256, 0, stream>>>(lin2W, l2WT, 1024, 1024);
  transpose_cast_k<<<dim3(12, 32), 256, 0, stream>>>(W3, W3T, 1024, 384);
  transpose_cast_k<<<dim3(2, 32), 256, 0, stream>>>(lin3W, l3WT, 1024, 64);

  // ---- CSR over dst (self loops appended)
  fill_ones_k<<<(N + 255) / 256, 256, 0, stream>>>(cursor, N);
  count_edges_k<<<(E + 255) / 256, 256, 0, stream>>>(dst, E, cursor);
  scan_k<<<1, 1024, 0, stream>>>(cursor, indptr, N);
  copy_k<<<(N + 255) / 256, 256, 0, stream>>>(indptr, cursor, N);
  scatter_k<<<(E + N + 255) / 256, 256, 0, stream>>>(src, dst, E, N, cursor, esrc);

  const int MB = (N + 127) / 128;
  // ---- Layer 1 (K=128)
  gemm_bf16<false><<<dim3(8, MB), 256, 0, stream>>>(x_bf, W1T, nullptr, h, N, 128, 1024);
  gemm_bf16<true ><<<dim3(8, MB), 256, 0, stream>>>(x_bf, l1WT, lin1b, skip, N, 128, 1024);
  logits_k<4, 256><<<N, 256, 0, stream>>>(h, a1s, a1d, sb, db);
  attn_k<4, 256, true, false><<<N, 256, 0, stream>>>(h, sb, db, indptr, esrc, b1, skip, act_bf);
  // ---- Layer 2 (K=1024)
  gemm_bf16<false><<<dim3(8, MB), 256, 0, stream>>>(act_bf, W2T, nullptr, h, N, 1024, 1024);
  gemm_bf16<true ><<<dim3(8, MB), 256, 0, stream>>>(act_bf, l2WT, lin2b, skip, N, 1024, 1024);
  logits_k<4, 256><<<N, 256, 0, stream>>>(h, a2s, a2d, sb, db);
  attn_k<4, 256, true, false><<<N, 256, 0, stream>>>(h, sb, db, indptr, esrc, b2, skip, act_bf);
  // ---- Layer 3 (K=1024, N=384 / 64)
  gemm_bf16<false><<<dim3(3, MB), 256, 0, stream>>>(act_bf, W3T, nullptr, h, N, 1024, 384);
  gemm_bf16<true ><<<dim3(1, MB), 256, 0, stream>>>(act_bf, l3WT, lin3b, skip, N, 1024, 64);
  logits_k<6, 64><<<N, 256, 0, stream>>>(h, a3s, a3d, sb, db);
  attn_k<6, 64, false, true><<<N, 256, 0, stream>>>(h, sb, db, indptr, esrc, b3, skip, d_out);
}

// Round 3
// 414.637 us; speedup vs baseline: 3.4073x; 1.2544x over previous
//
#include <hip/hip_runtime.h>
#include <math.h>

typedef unsigned short ushort_t;
typedef __attribute__((ext_vector_type(8))) short bf16x8;
typedef __attribute__((ext_vector_type(4))) float f32x4;

__device__ __forceinline__ ushort_t f2bf(float f) {
  unsigned u = __float_as_uint(f);
  unsigned r = (u + 0x7FFF + ((u >> 16) & 1)) >> 16;  // RNE
  return (ushort_t)r;
}
__device__ __forceinline__ float bf2f(ushort_t u) {
  return __uint_as_float(((unsigned)u) << 16);
}

__device__ __forceinline__ void gload_lds16(const void* g, void* l) {
  __builtin_amdgcn_global_load_lds(
      (const __attribute__((address_space(1))) void*)g,
      (__attribute__((address_space(3))) void*)l, 16, 0, 0);
}

// ---------------------------------------------------------------- CSR build
__global__ void fill_ones_k(int* __restrict__ p, int n) {
  int i = blockIdx.x * blockDim.x + threadIdx.x;
  if (i < n) p[i] = 1;  // self-loop contributes 1 to every node's in-degree
}

__global__ void count_edges_k(const int* __restrict__ dst, int E, int* __restrict__ cnt) {
  int i = blockIdx.x * blockDim.x + threadIdx.x;
  if (i < E) atomicAdd(&cnt[dst[i]], 1);
}

__global__ void scan_k(const int* __restrict__ cnt, int* __restrict__ indptr, int n) {
  __shared__ int lds[1024];
  __shared__ int carry_s;
  int t = threadIdx.x;
  if (t == 0) carry_s = 0;
  __syncthreads();
  for (int base = 0; base < n; base += 1024) {
    int i = base + t;
    int v = (i < n) ? cnt[i] : 0;
    lds[t] = v;
    __syncthreads();
    for (int off = 1; off < 1024; off <<= 1) {
      int add = (t >= off) ? lds[t - off] : 0;
      __syncthreads();
      lds[t] += add;
      __syncthreads();
    }
    int carry = carry_s;
    if (i < n) indptr[i] = carry + lds[t] - v;
    __syncthreads();
    if (t == 1023) carry_s = carry + lds[1023];
    __syncthreads();
  }
  if (t == 0) indptr[n] = carry_s;
}

__global__ void copy_k(const int* __restrict__ a, int* __restrict__ b, int n) {
  int i = blockIdx.x * blockDim.x + threadIdx.x;
  if (i < n) b[i] = a[i];
}

__global__ void scatter_k(const int* __restrict__ src, const int* __restrict__ dst, int E, int n,
                          int* __restrict__ cursor, int* __restrict__ esrc) {
  int i = blockIdx.x * blockDim.x + threadIdx.x;
  if (i < E) {
    int p = atomicAdd(&cursor[dst[i]], 1);
    esrc[p] = src[i];
  } else if (i < E + n) {
    int node = i - E;
    int p = atomicAdd(&cursor[node], 1);
    esrc[p] = node;  // self loop
  }
}

// ---------------------------------------------------------------- conversions
__global__ void cast_bf16_k(const float* __restrict__ in, ushort_t* __restrict__ out, int n4) {
  int i = blockIdx.x * blockDim.x + threadIdx.x;
  if (i < n4) {
    float4 v = ((const float4*)in)[i];
    ushort_t o0 = f2bf(v.x), o1 = f2bf(v.y), o2 = f2bf(v.z), o3 = f2bf(v.w);
    ushort_t* p = out + i * 4;
    p[0] = o0; p[1] = o1; p[2] = o2; p[3] = o3;
  }
}

// W [K][N] fp32 -> WT [N][K] bf16
__global__ __launch_bounds__(256) void transpose_cast_k(const float* __restrict__ W,
                                                        ushort_t* __restrict__ WT,
                                                        int K, int N) {
  __shared__ float tile[32][33];
  const int bx = blockIdx.x * 32;  // N dim
  const int by = blockIdx.y * 32;  // K dim
  const int tx = threadIdx.x & 31, ty = threadIdx.x >> 5;  // 32x8
  for (int i = ty; i < 32; i += 8) {
    int r = by + i, c = bx + tx;
    tile[i][tx] = (r < K && c < N) ? W[(size_t)r * N + c] : 0.f;
  }
  __syncthreads();
  for (int i = ty; i < 32; i += 8) {
    int r = bx + i, c = by + tx;
    if (r < N && c < K) WT[(size_t)r * K + c] = f2bf(tile[tx][i]);
  }
}

// ---------------------------------------------------------------- bf16 MFMA GEMM
// C[M,Nc] = A[M,K](bf16) @ BT[Nc,K](bf16)^T (+bias). 128x128 tile, BK=32,
// 256 thr (4 waves, 2x2), 16x16x32 MFMA, global_load_lds staging,
// XOR slot-swizzle for conflict-free ds_read_b128.
template<bool ADD_BIAS, bool OUT_BF16>
__global__ __launch_bounds__(256) void gemm_bf16(const ushort_t* __restrict__ A,
                                                 const ushort_t* __restrict__ BT,
                                                 const float* __restrict__ bias,
                                                 void* __restrict__ C_v,
                                                 int M, int K, int Nc) {
  __shared__ ushort_t As[128 * 32];
  __shared__ ushort_t Bs[128 * 32];
  const int bm = blockIdx.y * 128, bn = blockIdx.x * 128;
  const int t = threadIdx.x;
  const int l = t & 63, wid = t >> 6;
  const int wm = wid >> 1, wn = wid & 1;

  size_t goffA[2], goffB[2];
  for (int i = 0; i < 2; ++i) {
    int seg = wid * 2 + i;
    int row = seg * 16 + (l >> 2);
    int p = l & 3;
    int ls = p ^ ((row >> 1) & 3);  // inverse-swizzled source slot
    int ga = min(bm + row, M - 1);
    int gb = min(bn + row, Nc - 1);
    goffA[i] = (size_t)ga * K + ls * 8;
    goffB[i] = (size_t)gb * K + ls * 8;
  }
  ushort_t* ldsA0 = &As[(wid * 2 + 0) * 512];
  ushort_t* ldsA1 = &As[(wid * 2 + 1) * 512];
  ushort_t* ldsB0 = &Bs[(wid * 2 + 0) * 512];
  ushort_t* ldsB1 = &Bs[(wid * 2 + 1) * 512];

  const int lr = l & 15, s = l >> 4;
  int raddrA[4], raddrB[4];
  for (int m = 0; m < 4; ++m) {
    int rowA = wm * 64 + m * 16 + lr;
    raddrA[m] = rowA * 32 + (s ^ ((rowA >> 1) & 3)) * 8;
    int rowB = wn * 64 + m * 16 + lr;
    raddrB[m] = rowB * 32 + (s ^ ((rowB >> 1) & 3)) * 8;
  }

  f32x4 acc[4][4] = {};
  for (int k0 = 0; k0 < K; k0 += 32) {
    gload_lds16(A + goffA[0] + k0, ldsA0);
    gload_lds16(A + goffA[1] + k0, ldsA1);
    gload_lds16(BT + goffB[0] + k0, ldsB0);
    gload_lds16(BT + goffB[1] + k0, ldsB1);
    __syncthreads();
    bf16x8 a[4], b[4];
#pragma unroll
    for (int m = 0; m < 4; ++m) a[m] = *(const bf16x8*)&As[raddrA[m]];
#pragma unroll
    for (int n = 0; n < 4; ++n) b[n] = *(const bf16x8*)&Bs[raddrB[n]];
#pragma unroll
    for (int m = 0; m < 4; ++m)
#pragma unroll
      for (int n = 0; n < 4; ++n)
        acc[m][n] = __builtin_amdgcn_mfma_f32_16x16x32_bf16(a[m], b[n], acc[m][n], 0, 0, 0);
    __syncthreads();
  }

  // epilogue: C/D layout col = lane&15, row = (lane>>4)*4 + j
#pragma unroll
  for (int n = 0; n < 4; ++n) {
    int col = bn + wn * 64 + n * 16 + (l & 15);
    if (col >= Nc) continue;
    float bv = ADD_BIAS ? bias[col] : 0.f;
#pragma unroll
    for (int m = 0; m < 4; ++m) {
#pragma unroll
      for (int j = 0; j < 4; ++j) {
        int row = bm + wm * 64 + m * 16 + (l >> 4) * 4 + j;
        if (row < M) {
          float v = acc[m][n][j] + bv;
          if (OUT_BF16) ((ushort_t*)C_v)[(size_t)row * Nc + col] = f2bf(v);
          else          ((float*)C_v)[(size_t)row * Nc + col] = v;
        }
      }
    }
  }
}

// ---------------------------------------------------------------- logits s,d (bf16 h)
template<int H, int C>
__global__ __launch_bounds__(256) void logits_k(const ushort_t* __restrict__ h,
                                                const float* __restrict__ a_src,
                                                const float* __restrict__ a_dst,
                                                float* __restrict__ s, float* __restrict__ d) {
  const int node = blockIdx.x;
  const int wave = threadIdx.x >> 6, lane = threadIdx.x & 63;
  for (int hd = wave; hd < H; hd += 4) {
    float ss = 0.f, dd = 0.f;
    const ushort_t* hp = h + (size_t)node * H * C + hd * C;
    for (int c = lane * 4; c < C; c += 256) {
      ushort4 v = *(const ushort4*)&hp[c];
      float4 as = *(const float4*)&a_src[hd * C + c];
      float4 ad = *(const float4*)&a_dst[hd * C + c];
      float f0 = bf2f(v.x), f1 = bf2f(v.y), f2 = bf2f(v.z), f3 = bf2f(v.w);
      ss += f0 * as.x + f1 * as.y + f2 * as.z + f3 * as.w;
      dd += f0 * ad.x + f1 * ad.y + f2 * ad.z + f3 * ad.w;
    }
    for (int off = 32; off; off >>= 1) {
      ss += __shfl_xor(ss, off);
      dd += __shfl_xor(dd, off);
    }
    if (lane == 0) { s[node * H + hd] = ss; d[node * H + hd] = dd; }
  }
}

// ---------------------------------------------------------------- attention + aggregate
// !MEAN_HEADS: skip is bf16; writes bf16 [N][F] with ELU+skip+bias.
// MEAN_HEADS: skip is fp32; writes fp32 [N][C] final output.
template<int H, int C, bool ELU_OUT, bool MEAN_HEADS>
__global__ __launch_bounds__(256) void attn_k(const ushort_t* __restrict__ hfeat,
                                              const float* __restrict__ sbuf,
                                              const float* __restrict__ dbuf,
                                              const int* __restrict__ indptr,
                                              const int* __restrict__ esrc,
                                              const float* __restrict__ bias,
                                              const void* __restrict__ skip_v,
                                              void* __restrict__ out_v) {
  constexpr int F = H * C;
  constexpr int CPT = (F + 255) / 256;   // 4 (F=1024) or 2 (F=384)
  constexpr int CH = 256 / H;            // edge chunk: 64 (H=4), 42 (H=6)
  __shared__ float m_l[H], invden_l[H], d_l[H];
  __shared__ float alpha_l[CH * H];
  __shared__ int src_l[CH];
  __shared__ float accs[MEAN_HEADS ? F : 4];

  const int node = blockIdx.x;
  const int t = threadIdx.x;
  const int beg = indptr[node];
  const int deg = indptr[node + 1] - beg;
  if (t < H) d_l[t] = dbuf[node * H + t];
  __syncthreads();

  const int wave = t >> 6, lane = t & 63;
  for (int hd = wave; hd < H; hd += 4) {
    const float dn = d_l[hd];
    float mx = -1e30f;
    for (int i = lane; i < deg; i += 64) {
      int se = esrc[beg + i];
      float e = sbuf[se * H + hd] + dn;
      e = fmaxf(e, 0.2f * e);  // leaky relu
      mx = fmaxf(mx, e);
    }
    for (int off = 32; off; off >>= 1) mx = fmaxf(mx, __shfl_xor(mx, off));
    float den = 0.f;
    for (int i = lane; i < deg; i += 64) {
      int se = esrc[beg + i];
      float e = sbuf[se * H + hd] + dn;
      e = fmaxf(e, 0.2f * e);
      den += __expf(e - mx);
    }
    for (int off = 32; off; off >>= 1) den += __shfl_xor(den, off);
    if (lane == 0) { m_l[hd] = mx; invden_l[hd] = 1.f / den; }
  }
  __syncthreads();

  float acc[CPT] = {};
  const int c0 = t * CPT;
  const int myhead = c0 / C;
  for (int cb = 0; cb < deg; cb += CH) {
    const int ce = min(CH, deg - cb);
    if (t < ce * H) {
      int e_i = t / H, hd = t % H;
      int se = esrc[beg + cb + e_i];
      if (hd == 0) src_l[e_i] = se;
      float e = sbuf[se * H + hd] + d_l[hd];
      e = fmaxf(e, 0.2f * e);
      alpha_l[e_i * H + hd] = __expf(e - m_l[hd]) * invden_l[hd];
    }
    __syncthreads();
    if (c0 < F) {
      for (int e_i = 0; e_i < ce; ++e_i) {
        int se = src_l[e_i];
        float al = alpha_l[e_i * H + myhead];
        const ushort_t* hp = hfeat + (size_t)se * F + c0;
        if (CPT == 4) {
          ushort4 v = *(const ushort4*)hp;
          acc[0] += al * bf2f(v.x); acc[1] += al * bf2f(v.y);
          acc[2] += al * bf2f(v.z); acc[3] += al * bf2f(v.w);
        } else {
          ushort2 v = *(const ushort2*)hp;
          acc[0] += al * bf2f(v.x); acc[1] += al * bf2f(v.y);
        }
      }
    }
    __syncthreads();
  }

  if (!MEAN_HEADS) {
    if (c0 < F) {
      const ushort_t* skip = (const ushort_t*)skip_v;
      ushort_t* out = (ushort_t*)out_v;
      ushort4 sv = *(const ushort4*)&skip[(size_t)node * F + c0];
      float sk[4] = {bf2f(sv.x), bf2f(sv.y), bf2f(sv.z), bf2f(sv.w)};
      ushort_t r[CPT];
#pragma unroll
      for (int j = 0; j < CPT; ++j) {
        float x = acc[j] + bias[c0 + j] + sk[j];
        if (ELU_OUT) x = x > 0.f ? x : __expf(x) - 1.f;
        r[j] = f2bf(x);
      }
      ushort4 o; o.x = r[0]; o.y = r[1]; o.z = r[2]; o.w = r[3];
      *(ushort4*)&out[(size_t)node * F + c0] = o;
    }
  } else {
    const float* skip = (const float*)skip_v;
    float* out = (float*)out_v;
    if (c0 < F) { accs[c0] = acc[0]; accs[c0 + 1] = acc[1]; }
    __syncthreads();
    if (t < C) {
      float sum = 0.f;
#pragma unroll
      for (int hd = 0; hd < H; ++hd) sum += accs[hd * C + t];
      out[(size_t)node * C + t] = sum * (1.f / (float)H) + bias[t] + skip[(size_t)node * C + t];
    }
  }
}

// ---------------------------------------------------------------- launch
extern "C" void kernel_launch(void* const* d_in, const int* in_sizes, int n_in,
                              void* d_out, int out_size, void* d_ws, size_t ws_size,
                              hipStream_t stream) {
  const float* x      = (const float*)d_in[0];
  const int*   ei     = (const int*)d_in[1];
  const float* W1     = (const float*)d_in[2];
  const float* a1s    = (const float*)d_in[3];
  const float* a1d    = (const float*)d_in[4];
  const float* b1     = (const float*)d_in[5];
  const float* lin1W  = (const float*)d_in[6];
  const float* lin1b  = (const float*)d_in[7];
  const float* W2     = (const float*)d_in[8];
  const float* a2s    = (const float*)d_in[9];
  const float* a2d    = (const float*)d_in[10];
  const float* b2     = (const float*)d_in[11];
  const float* lin2W  = (const float*)d_in[12];
  const float* lin2b  = (const float*)d_in[13];
  const float* W3     = (const float*)d_in[14];
  const float* a3s    = (const float*)d_in[15];
  const float* a3d    = (const float*)d_in[16];
  const float* b3     = (const float*)d_in[17];
  const float* lin3W  = (const float*)d_in[18];
  const float* lin3b  = (const float*)d_in[19];

  const int N = in_sizes[0] / 128;
  const int E = in_sizes[1] / 2;
  const int* src = ei;
  const int* dst = ei + E;

  char* ws = (char*)d_ws;
  size_t off = 0;
  auto alloc = [&](size_t bytes) -> void* {
    void* p = ws + off;
    off += (bytes + 255) & ~(size_t)255;
    return p;
  };
  ushort_t* h_bf    = (ushort_t*)alloc((size_t)N * 1024 * 2);
  ushort_t* skip_bf = (ushort_t*)alloc((size_t)N * 1024 * 2);
  float*    skip3   = (float*)alloc((size_t)N * 64 * 4);
  ushort_t* act_bf  = (ushort_t*)alloc((size_t)N * 1024 * 2);
  ushort_t* x_bf    = (ushort_t*)alloc((size_t)N * 128 * 2);
  ushort_t* W1T     = (ushort_t*)alloc((size_t)1024 * 128 * 2);
  ushort_t* l1WT    = (ushort_t*)alloc((size_t)1024 * 128 * 2);
  ushort_t* W2T     = (ushort_t*)alloc((size_t)1024 * 1024 * 2);
  ushort_t* l2WT    = (ushort_t*)alloc((size_t)1024 * 1024 * 2);
  ushort_t* W3T     = (ushort_t*)alloc((size_t)384 * 1024 * 2);
  ushort_t* l3WT    = (ushort_t*)alloc((size_t)64 * 1024 * 2);
  float*    sb      = (float*)alloc((size_t)N * 6 * 4);
  float*    db      = (float*)alloc((size_t)N * 6 * 4);
  int*      indptr  = (int*)alloc((size_t)(N + 1) * 4);
  int*      cursor  = (int*)alloc((size_t)N * 4);
  int*      esrc    = (int*)alloc((size_t)(E + N) * 4);

  // ---- conversions (weights once; x once)
  cast_bf16_k<<<(N * 128 / 4 + 255) / 256, 256, 0, stream>>>(x, x_bf, N * 128 / 4);
  transpose_cast_k<<<dim3(32, 4), 256, 0, stream>>>(W1, W1T, 128, 1024);
  transpose_cast_k<<<dim3(32, 4), 256, 0, stream>>>(lin1W, l1WT, 128, 1024);
  transpose_cast_k<<<dim3(32, 32), 256, 0, stream>>>(W2, W2T, 1024, 1024);
  transpose_cast_k<<<dim3(32, 32), 256, 0, stream>>>(lin2W, l2WT, 1024, 1024);
  transpose_cast_k<<<dim3(12, 32), 256, 0, stream>>>(W3, W3T, 1024, 384);
  transpose_cast_k<<<dim3(2, 32), 256, 0, stream>>>(lin3W, l3WT, 1024, 64);

  // ---- CSR over dst (self loops appended)
  fill_ones_k<<<(N + 255) / 256, 256, 0, stream>>>(cursor, N);
  count_edges_k<<<(E + 255) / 256, 256, 0, stream>>>(dst, E, cursor);
  scan_k<<<1, 1024, 0, stream>>>(cursor, indptr, N);
  copy_k<<<(N + 255) / 256, 256, 0, stream>>>(indptr, cursor, N);
  scatter_k<<<(E + N + 255) / 256, 256, 0, stream>>>(src, dst, E, N, cursor, esrc);

  const int MB = (N + 127) / 128;
  // ---- Layer 1 (K=128)
  gemm_bf16<false, true><<<dim3(8, MB), 256, 0, stream>>>(x_bf, W1T, nullptr, h_bf, N, 128, 1024);
  gemm_bf16<true,  true><<<dim3(8, MB), 256, 0, stream>>>(x_bf, l1WT, lin1b, skip_bf, N, 128, 1024);
  logits_k<4, 256><<<N, 256, 0, stream>>>(h_bf, a1s, a1d, sb, db);
  attn_k<4, 256, true, false><<<N, 256, 0, stream>>>(h_bf, sb, db, indptr, esrc, b1, skip_bf, act_bf);
  // ---- Layer 2 (K=1024)
  gemm_bf16<false, true><<<dim3(8, MB), 256, 0, stream>>>(act_bf, W2T, nullptr, h_bf, N, 1024, 1024);
  gemm_bf16<true,  true><<<dim3(8, MB), 256, 0, stream>>>(act_bf, l2WT, lin2b, skip_bf, N, 1024, 1024);
  logits_k<4, 256><<<N, 256, 0, stream>>>(h_bf, a2s, a2d, sb, db);
  attn_k<4, 256, true, false><<<N, 256, 0, stream>>>(h_bf, sb, db, indptr, esrc, b2, skip_bf, act_bf);
  // ---- Layer 3 (K=1024, N=384 / 64)
  gemm_bf16<false, true><<<dim3(3, MB), 256, 0, stream>>>(act_bf, W3T, nullptr, h_bf, N, 1024, 384);
  gemm_bf16<true, false><<<dim3(1, MB), 256, 0, stream>>>(act_bf, l3WT, lin3b, skip3, N, 1024, 64);
  logits_k<6, 64><<<N, 256, 0, stream>>>(h_bf, a3s, a3d, sb, db);
  attn_k<6, 64, false, true><<<N, 256, 0, stream>>>(h_bf, sb, db, indptr, esrc, b3, skip3, d_out);
}

// Round 4
// 401.364 us; speedup vs baseline: 3.5200x; 1.0331x over previous
//
#include <hip/hip_runtime.h>
#include <math.h>

typedef unsigned short ushort_t;
typedef __attribute__((ext_vector_type(8))) short bf16x8;
typedef __attribute__((ext_vector_type(4))) float f32x4;

__device__ __forceinline__ ushort_t f2bf(float f) {
  unsigned u = __float_as_uint(f);
  unsigned r = (u + 0x7FFF + ((u >> 16) & 1)) >> 16;  // RNE
  return (ushort_t)r;
}
__device__ __forceinline__ float bf2f(ushort_t u) {
  return __uint_as_float(((unsigned)u) << 16);
}

__device__ __forceinline__ void gload_lds16(const void* g, void* l) {
  __builtin_amdgcn_global_load_lds(
      (const __attribute__((address_space(1))) void*)g,
      (__attribute__((address_space(3))) void*)l, 16, 0, 0);
}

// ---------------------------------------------------------------- init: cursor=1, zero s/d buffers
__global__ void init_k(int* __restrict__ cursor, int n, float* __restrict__ z, int nz) {
  int i = blockIdx.x * blockDim.x + threadIdx.x;
  if (i < n) cursor[i] = 1;  // self-loop contributes 1 to in-degree
  if (i < nz) z[i] = 0.f;
}

__global__ void count_edges_k(const int* __restrict__ dst, int E, int* __restrict__ cnt) {
  int i = blockIdx.x * blockDim.x + threadIdx.x;
  if (i < E) atomicAdd(&cnt[dst[i]], 1);
}

// exclusive scan; writes indptr AND cursor
__global__ void scan_k(const int* __restrict__ cnt, int* __restrict__ indptr,
                       int* __restrict__ cursor, int n) {
  __shared__ int lds[1024];
  __shared__ int carry_s;
  int t = threadIdx.x;
  if (t == 0) carry_s = 0;
  __syncthreads();
  for (int base = 0; base < n; base += 1024) {
    int i = base + t;
    int v = (i < n) ? cnt[i] : 0;
    lds[t] = v;
    __syncthreads();
    for (int off = 1; off < 1024; off <<= 1) {
      int add = (t >= off) ? lds[t - off] : 0;
      __syncthreads();
      lds[t] += add;
      __syncthreads();
    }
    int carry = carry_s;
    if (i < n) { int e = carry + lds[t] - v; indptr[i] = e; cursor[i] = e; }
    __syncthreads();
    if (t == 1023) carry_s = carry + lds[1023];
    __syncthreads();
  }
  if (t == 0) indptr[n] = carry_s;
}

__global__ void scatter_k(const int* __restrict__ src, const int* __restrict__ dst, int E, int n,
                          int* __restrict__ cursor, int* __restrict__ esrc) {
  int i = blockIdx.x * blockDim.x + threadIdx.x;
  if (i < E) {
    int p = atomicAdd(&cursor[dst[i]], 1);
    esrc[p] = src[i];
  } else if (i < E + n) {
    int node = i - E;
    int p = atomicAdd(&cursor[node], 1);
    esrc[p] = node;  // self loop
  }
}

// ---------------------------------------------------------------- conversions
__global__ void cast_bf16_k(const float* __restrict__ in, ushort_t* __restrict__ out, int n4) {
  int i = blockIdx.x * blockDim.x + threadIdx.x;
  if (i < n4) {
    float4 v = ((const float4*)in)[i];
    ushort_t o0 = f2bf(v.x), o1 = f2bf(v.y), o2 = f2bf(v.z), o3 = f2bf(v.w);
    ushort_t* p = out + i * 4;
    p[0] = o0; p[1] = o1; p[2] = o2; p[3] = o3;
  }
}

// Two fp32 [K][Na],[K][Nb] -> one bf16 [Na+Nb][K] (concatenated transpose).
// All of Na, Nb, K multiples of 32.
__global__ __launch_bounds__(256) void transpose_dual_k(const float* __restrict__ Wa, int Na,
                                                        const float* __restrict__ Wb, int Nb,
                                                        int K, ushort_t* __restrict__ dst) {
  __shared__ float tile[32][33];
  const int bx = blockIdx.x * 32;  // n dim (global, 0..Na+Nb)
  const int by = blockIdx.y * 32;  // k dim
  const int tx = threadIdx.x & 31, ty = threadIdx.x >> 5;  // 32x8
  const bool isB = bx >= Na;       // blocks are 32-aligned; Na is a multiple of 32
  const float* W = isB ? Wb : Wa;
  const int Nw = isB ? Nb : Na;
  const int nc = bx - (isB ? Na : 0) + tx;
  for (int i = ty; i < 32; i += 8)
    tile[i][tx] = W[(size_t)(by + i) * Nw + nc];
  __syncthreads();
  for (int i = ty; i < 32; i += 8)
    dst[(size_t)(bx + i) * K + by + tx] = f2bf(tile[tx][i]);
}

// ---------------------------------------------------------------- fused MFMA GEMM
// A[M,K](bf16) @ Bcat[NCT,K]^T. Cols [0,HC) -> h_out (bf16, no bias).
// Cols [HC,HC+SC) -> skip_out (+skip_bias), bf16 or fp32. Cols >= HC+SC discarded.
// If LOGITS: per-row s,d = h-row . a_src/a_dst (H=4, C=256) atomically accumulated.
template<int NCT, int HC, int SC, bool LOGITS, bool SKIP_BF16>
__global__ __launch_bounds__(256) void gemm_fused(const ushort_t* __restrict__ A,
                                                  const ushort_t* __restrict__ BT,
                                                  const float* __restrict__ skip_bias,
                                                  const float* __restrict__ a_src,
                                                  const float* __restrict__ a_dst,
                                                  float* __restrict__ sb,
                                                  float* __restrict__ db,
                                                  ushort_t* __restrict__ h_out,
                                                  void* __restrict__ skip_out,
                                                  int M, int K) {
  __shared__ ushort_t As[128 * 32];
  __shared__ ushort_t Bs[128 * 32];
  const int bm = blockIdx.y * 128, bn = blockIdx.x * 128;
  const int t = threadIdx.x;
  const int l = t & 63, wid = t >> 6;
  const int wm = wid >> 1, wn = wid & 1;

  size_t goffA[2], goffB[2];
  for (int i = 0; i < 2; ++i) {
    int seg = wid * 2 + i;
    int row = seg * 16 + (l >> 2);
    int p = l & 3;
    int ls = p ^ ((row >> 1) & 3);  // inverse-swizzled source slot
    int ga = min(bm + row, M - 1);
    int gb = min(bn + row, NCT - 1);
    goffA[i] = (size_t)ga * K + ls * 8;
    goffB[i] = (size_t)gb * K + ls * 8;
  }
  ushort_t* ldsA0 = &As[(wid * 2 + 0) * 512];
  ushort_t* ldsA1 = &As[(wid * 2 + 1) * 512];
  ushort_t* ldsB0 = &Bs[(wid * 2 + 0) * 512];
  ushort_t* ldsB1 = &Bs[(wid * 2 + 1) * 512];

  const int lr = l & 15, s = l >> 4;
  int raddrA[4], raddrB[4];
  for (int m = 0; m < 4; ++m) {
    int rowA = wm * 64 + m * 16 + lr;
    raddrA[m] = rowA * 32 + (s ^ ((rowA >> 1) & 3)) * 8;
    int rowB = wn * 64 + m * 16 + lr;
    raddrB[m] = rowB * 32 + (s ^ ((rowB >> 1) & 3)) * 8;
  }

  f32x4 acc[4][4] = {};
  for (int k0 = 0; k0 < K; k0 += 32) {
    gload_lds16(A + goffA[0] + k0, ldsA0);
    gload_lds16(A + goffA[1] + k0, ldsA1);
    gload_lds16(BT + goffB[0] + k0, ldsB0);
    gload_lds16(BT + goffB[1] + k0, ldsB1);
    __syncthreads();
    bf16x8 a[4], b[4];
#pragma unroll
    for (int m = 0; m < 4; ++m) a[m] = *(const bf16x8*)&As[raddrA[m]];
#pragma unroll
    for (int n = 0; n < 4; ++n) b[n] = *(const bf16x8*)&Bs[raddrB[n]];
#pragma unroll
    for (int m = 0; m < 4; ++m)
#pragma unroll
      for (int n = 0; n < 4; ++n)
        acc[m][n] = __builtin_amdgcn_mfma_f32_16x16x32_bf16(a[m], b[n], acc[m][n], 0, 0, 0);
    __syncthreads();
  }

  // ---- fused logits: s/d partial = sum over this wave's 64 cols of acc * a
  const int colw = bn + wn * 64;  // wave's col base (64-aligned -> single head)
  if (LOGITS && colw < HC) {
    const int head = colw >> 8;
    float as[4], ad[4];
#pragma unroll
    for (int n = 0; n < 4; ++n) {
      int c = (colw + n * 16 + lr) & 255;
      as[n] = a_src[head * 256 + c];
      ad[n] = a_dst[head * 256 + c];
    }
#pragma unroll
    for (int m = 0; m < 4; ++m) {
#pragma unroll
      for (int j = 0; j < 4; ++j) {
        float sp = 0.f, dp = 0.f;
#pragma unroll
        for (int n = 0; n < 4; ++n) { sp += acc[m][n][j] * as[n]; dp += acc[m][n][j] * ad[n]; }
#pragma unroll
        for (int off = 1; off <= 8; off <<= 1) {
          sp += __shfl_xor(sp, off);
          dp += __shfl_xor(dp, off);
        }
        if (lr == 0) {
          int row = bm + wm * 64 + m * 16 + (l >> 4) * 4 + j;
          if (row < M) {
            atomicAdd(&sb[row * 4 + head], sp);
            atomicAdd(&db[row * 4 + head], dp);
          }
        }
      }
    }
  }

  // ---- stores: C/D layout col = lane&15, row = (lane>>4)*4 + j
#pragma unroll
  for (int n = 0; n < 4; ++n) {
    int col = bn + wn * 64 + n * 16 + lr;
    if (col >= HC + SC) continue;
    const bool is_h = col < HC;
    float bv = is_h ? 0.f : skip_bias[col - HC];
#pragma unroll
    for (int m = 0; m < 4; ++m) {
#pragma unroll
      for (int j = 0; j < 4; ++j) {
        int row = bm + wm * 64 + m * 16 + (l >> 4) * 4 + j;
        if (row >= M) continue;
        float v = acc[m][n][j] + bv;
        if (is_h) {
          h_out[(size_t)row * HC + col] = f2bf(v);
        } else if (SKIP_BF16) {
          ((ushort_t*)skip_out)[(size_t)row * SC + (col - HC)] = f2bf(v);
        } else {
          ((float*)skip_out)[(size_t)row * SC + (col - HC)] = v;
        }
      }
    }
  }
}

// ---------------------------------------------------------------- logits (layer 3 only, bf16 h)
template<int H, int C>
__global__ __launch_bounds__(256) void logits_k(const ushort_t* __restrict__ h,
                                                const float* __restrict__ a_src,
                                                const float* __restrict__ a_dst,
                                                float* __restrict__ s, float* __restrict__ d) {
  const int node = blockIdx.x;
  const int wave = threadIdx.x >> 6, lane = threadIdx.x & 63;
  for (int hd = wave; hd < H; hd += 4) {
    float ss = 0.f, dd = 0.f;
    const ushort_t* hp = h + (size_t)node * H * C + hd * C;
    for (int c = lane * 4; c < C; c += 256) {
      ushort4 v = *(const ushort4*)&hp[c];
      float4 as = *(const float4*)&a_src[hd * C + c];
      float4 ad = *(const float4*)&a_dst[hd * C + c];
      float f0 = bf2f(v.x), f1 = bf2f(v.y), f2 = bf2f(v.z), f3 = bf2f(v.w);
      ss += f0 * as.x + f1 * as.y + f2 * as.z + f3 * as.w;
      dd += f0 * ad.x + f1 * ad.y + f2 * ad.z + f3 * ad.w;
    }
    for (int off = 32; off; off >>= 1) {
      ss += __shfl_xor(ss, off);
      dd += __shfl_xor(dd, off);
    }
    if (lane == 0) { s[node * H + hd] = ss; d[node * H + hd] = dd; }
  }
}

// ---------------------------------------------------------------- attention + aggregate
template<int H, int C, bool ELU_OUT, bool MEAN_HEADS>
__global__ __launch_bounds__(256) void attn_k(const ushort_t* __restrict__ hfeat,
                                              const float* __restrict__ sbuf,
                                              const float* __restrict__ dbuf,
                                              const int* __restrict__ indptr,
                                              const int* __restrict__ esrc,
                                              const float* __restrict__ bias,
                                              const void* __restrict__ skip_v,
                                              void* __restrict__ out_v) {
  constexpr int F = H * C;
  constexpr int CPT = (F + 255) / 256;   // 4 (F=1024) or 2 (F=384)
  constexpr int CH = 256 / H;            // edge chunk: 64 (H=4), 42 (H=6)
  __shared__ float m_l[H], invden_l[H], d_l[H];
  __shared__ float alpha_l[CH * H];
  __shared__ int src_l[CH];
  __shared__ float accs[MEAN_HEADS ? F : 4];

  const int node = blockIdx.x;
  const int t = threadIdx.x;
  const int beg = indptr[node];
  const int deg = indptr[node + 1] - beg;
  if (t < H) d_l[t] = dbuf[node * H + t];
  __syncthreads();

  const int wave = t >> 6, lane = t & 63;
  for (int hd = wave; hd < H; hd += 4) {
    const float dn = d_l[hd];
    float mx = -1e30f;
    for (int i = lane; i < deg; i += 64) {
      int se = esrc[beg + i];
      float e = sbuf[se * H + hd] + dn;
      e = fmaxf(e, 0.2f * e);  // leaky relu
      mx = fmaxf(mx, e);
    }
    for (int off = 32; off; off >>= 1) mx = fmaxf(mx, __shfl_xor(mx, off));
    float den = 0.f;
    for (int i = lane; i < deg; i += 64) {
      int se = esrc[beg + i];
      float e = sbuf[se * H + hd] + dn;
      e = fmaxf(e, 0.2f * e);
      den += __expf(e - mx);
    }
    for (int off = 32; off; off >>= 1) den += __shfl_xor(den, off);
    if (lane == 0) { m_l[hd] = mx; invden_l[hd] = 1.f / den; }
  }
  __syncthreads();

  float acc[CPT] = {};
  const int c0 = t * CPT;
  const int myhead = c0 / C;
  for (int cb = 0; cb < deg; cb += CH) {
    const int ce = min(CH, deg - cb);
    if (t < ce * H) {
      int e_i = t / H, hd = t % H;
      int se = esrc[beg + cb + e_i];
      if (hd == 0) src_l[e_i] = se;
      float e = sbuf[se * H + hd] + d_l[hd];
      e = fmaxf(e, 0.2f * e);
      alpha_l[e_i * H + hd] = __expf(e - m_l[hd]) * invden_l[hd];
    }
    __syncthreads();
    if (c0 < F) {
      for (int e_i = 0; e_i < ce; ++e_i) {
        int se = src_l[e_i];
        float al = alpha_l[e_i * H + myhead];
        const ushort_t* hp = hfeat + (size_t)se * F + c0;
        if (CPT == 4) {
          ushort4 v = *(const ushort4*)hp;
          acc[0] += al * bf2f(v.x); acc[1] += al * bf2f(v.y);
          acc[2] += al * bf2f(v.z); acc[3] += al * bf2f(v.w);
        } else {
          ushort2 v = *(const ushort2*)hp;
          acc[0] += al * bf2f(v.x); acc[1] += al * bf2f(v.y);
        }
      }
    }
    __syncthreads();
  }

  if (!MEAN_HEADS) {
    if (c0 < F) {
      const ushort_t* skip = (const ushort_t*)skip_v;
      ushort_t* out = (ushort_t*)out_v;
      ushort4 sv = *(const ushort4*)&skip[(size_t)node * F + c0];
      float sk[4] = {bf2f(sv.x), bf2f(sv.y), bf2f(sv.z), bf2f(sv.w)};
      ushort_t r[CPT];
#pragma unroll
      for (int j = 0; j < CPT; ++j) {
        float x = acc[j] + bias[c0 + j] + sk[j];
        if (ELU_OUT) x = x > 0.f ? x : __expf(x) - 1.f;
        r[j] = f2bf(x);
      }
      ushort4 o; o.x = r[0]; o.y = r[1]; o.z = r[2]; o.w = r[3];
      *(ushort4*)&out[(size_t)node * F + c0] = o;
    }
  } else {
    const float* skip = (const float*)skip_v;
    float* out = (float*)out_v;
    if (c0 < F) { accs[c0] = acc[0]; accs[c0 + 1] = acc[1]; }
    __syncthreads();
    if (t < C) {
      float sum = 0.f;
#pragma unroll
      for (int hd = 0; hd < H; ++hd) sum += accs[hd * C + t];
      out[(size_t)node * C + t] = sum * (1.f / (float)H) + bias[t] + skip[(size_t)node * C + t];
    }
  }
}

// ---------------------------------------------------------------- launch
extern "C" void kernel_launch(void* const* d_in, const int* in_sizes, int n_in,
                              void* d_out, int out_size, void* d_ws, size_t ws_size,
                              hipStream_t stream) {
  const float* x      = (const float*)d_in[0];
  const int*   ei     = (const int*)d_in[1];
  const float* W1     = (const float*)d_in[2];
  const float* a1s    = (const float*)d_in[3];
  const float* a1d    = (const float*)d_in[4];
  const float* b1     = (const float*)d_in[5];
  const float* lin1W  = (const float*)d_in[6];
  const float* lin1b  = (const float*)d_in[7];
  const float* W2     = (const float*)d_in[8];
  const float* a2s    = (const float*)d_in[9];
  const float* a2d    = (const float*)d_in[10];
  const float* b2     = (const float*)d_in[11];
  const float* lin2W  = (const float*)d_in[12];
  const float* lin2b  = (const float*)d_in[13];
  const float* W3     = (const float*)d_in[14];
  const float* a3s    = (const float*)d_in[15];
  const float* a3d    = (const float*)d_in[16];
  const float* b3     = (const float*)d_in[17];
  const float* lin3W  = (const float*)d_in[18];
  const float* lin3b  = (const float*)d_in[19];

  const int N = in_sizes[0] / 128;
  const int E = in_sizes[1] / 2;
  const int* src = ei;
  const int* dst = ei + E;

  char* ws = (char*)d_ws;
  size_t off = 0;
  auto alloc = [&](size_t bytes) -> void* {
    void* p = ws + off;
    off += (bytes + 255) & ~(size_t)255;
    return p;
  };
  ushort_t* h_bf    = (ushort_t*)alloc((size_t)N * 1024 * 2);
  ushort_t* skip_bf = (ushort_t*)alloc((size_t)N * 1024 * 2);
  float*    skip3   = (float*)alloc((size_t)N * 64 * 4);
  ushort_t* act_bf  = (ushort_t*)alloc((size_t)N * 1024 * 2);
  ushort_t* x_bf    = (ushort_t*)alloc((size_t)N * 128 * 2);
  ushort_t* W1cat   = (ushort_t*)alloc((size_t)2048 * 128 * 2);
  ushort_t* W2cat   = (ushort_t*)alloc((size_t)2048 * 1024 * 2);
  ushort_t* W3cat   = (ushort_t*)alloc((size_t)512 * 1024 * 2);   // rows 448..511 pad (unread cols guarded)
  float*    sd12    = (float*)alloc((size_t)4 * N * 4 * 4);       // sb1,db1,sb2,db2 contiguous
  float*    sb1 = sd12, *db1 = sd12 + N * 4, *sb2 = sd12 + 2 * N * 4, *db2 = sd12 + 3 * N * 4;
  float*    sb3     = (float*)alloc((size_t)N * 6 * 4);
  float*    db3     = (float*)alloc((size_t)N * 6 * 4);
  int*      indptr  = (int*)alloc((size_t)(N + 1) * 4);
  int*      cursor  = (int*)alloc((size_t)N * 4);
  int*      esrc    = (int*)alloc((size_t)(E + N) * 4);

  const int NZ = 4 * N * 4;  // floats to zero (sb1,db1,sb2,db2)
  // ---- init (cursor=1 for self loops; zero logit accumulators)
  init_k<<<(max(N, NZ) + 255) / 256, 256, 0, stream>>>(cursor, N, sd12, NZ);
  count_edges_k<<<(E + 255) / 256, 256, 0, stream>>>(dst, E, cursor);
  scan_k<<<1, 1024, 0, stream>>>(cursor, indptr, cursor, N);
  scatter_k<<<(E + N + 255) / 256, 256, 0, stream>>>(src, dst, E, N, cursor, esrc);

  // ---- conversions
  cast_bf16_k<<<(N * 128 / 4 + 255) / 256, 256, 0, stream>>>(x, x_bf, N * 128 / 4);
  transpose_dual_k<<<dim3(64, 4), 256, 0, stream>>>(W1, 1024, lin1W, 1024, 128, W1cat);
  transpose_dual_k<<<dim3(64, 32), 256, 0, stream>>>(W2, 1024, lin2W, 1024, 1024, W2cat);
  transpose_dual_k<<<dim3(14, 32), 256, 0, stream>>>(W3, 384, lin3W, 64, 1024, W3cat);

  const int MB = (N + 127) / 128;
  // ---- Layer 1: fused GEMM (h|skip) + logits atomics
  gemm_fused<2048, 1024, 1024, true, true><<<dim3(16, MB), 256, 0, stream>>>(
      x_bf, W1cat, lin1b, a1s, a1d, sb1, db1, h_bf, skip_bf, N, 128);
  attn_k<4, 256, true, false><<<N, 256, 0, stream>>>(h_bf, sb1, db1, indptr, esrc, b1, skip_bf, act_bf);
  // ---- Layer 2
  gemm_fused<2048, 1024, 1024, true, true><<<dim3(16, MB), 256, 0, stream>>>(
      act_bf, W2cat, lin2b, a2s, a2d, sb2, db2, h_bf, skip_bf, N, 1024);
  attn_k<4, 256, true, false><<<N, 256, 0, stream>>>(h_bf, sb2, db2, indptr, esrc, b2, skip_bf, act_bf);
  // ---- Layer 3 (H=6, C=64; logits via separate pass)
  gemm_fused<512, 384, 64, false, false><<<dim3(4, MB), 256, 0, stream>>>(
      act_bf, W3cat, lin3b, nullptr, nullptr, nullptr, nullptr, h_bf, skip3, N, 1024);
  logits_k<6, 64><<<N, 256, 0, stream>>>(h_bf, a3s, a3d, sb3, db3);
  attn_k<6, 64, false, true><<<N, 256, 0, stream>>>(h_bf, sb3, db3, indptr, esrc, b3, skip3, d_out);
}